// Round 8
// baseline (181.899 us; speedup 1.0000x reference)
//
#include <hip/hip_runtime.h>
#include <math.h>

#define T_STEPS 32
#define BATCH 64

// ws layout (floats)
#define WS_WXQ 0        // [8][512]
#define WS_WHQ 4096     // [8][512]
#define WS_BQ  8192     // [8]
#define WS_U   8208     // 128 matrices * 8 floats (id = wv*32 + gl*16 + d*8 + w)
#define WS_XQ  9232     // [32*64][8]

typedef float v2f __attribute__((ext_vector_type(2)));
typedef unsigned int u32x2 __attribute__((ext_vector_type(2)));

struct c32 { float x, y; };
__device__ __forceinline__ c32 cmul(c32 a, c32 b){ return {a.x*b.x - a.y*b.y, a.x*b.y + a.y*b.x}; }
__device__ __forceinline__ c32 cadd(c32 a, c32 b){ return {a.x+b.x, a.y+b.y}; }

__device__ __forceinline__ v2f mkv(float x, float y){ v2f r; r.x = x; r.y = y; return r; }
__device__ __forceinline__ float fast_sigmoid(float x){ return 1.f/(1.f + __expf(-x)); }
__device__ __forceinline__ float fast_tanh(float x){ float e = __expf(2.f*x); return 1.f - 2.f/(e+1.f); }

template<int C> __device__ __forceinline__ float dppf(float v){
    return __int_as_float(__builtin_amdgcn_mov_dpp(__float_as_int(v), C, 0xF, 0xF, true));
}
__device__ __forceinline__ float swap16(float v, int lane){
#if __has_builtin(__builtin_amdgcn_permlane16_swap)
    u32x2 r = __builtin_amdgcn_permlane16_swap(__float_as_uint(v), __float_as_uint(v), false, false);
    return __uint_as_float((lane & 16) ? r.x : r.y);
#else
    return __shfl_xor(v, 16);
#endif
}
__device__ __forceinline__ float swap32(float v, int lane){
#if __has_builtin(__builtin_amdgcn_permlane32_swap)
    u32x2 r = __builtin_amdgcn_permlane32_swap(__float_as_uint(v), __float_as_uint(v), false, false);
    return __uint_as_float((lane & 32) ? r.x : r.y);
#else
    return __shfl_xor(v, 32);
#endif
}
template<int LM> __device__ __forceinline__ float lanexor(float v, int lane){
    if constexpr (LM == 1)       return dppf<0xB1>(v);                // quad_perm {1,0,3,2}
    else if constexpr (LM == 2)  return dppf<0x4E>(v);                // quad_perm {2,3,0,1}
    else if constexpr (LM == 4)  return dppf<0x1B>(dppf<0x141>(v));
    else if constexpr (LM == 8)  return dppf<0x128>(v);
    else if constexpr (LM == 16) return swap16(v, lane);
    else                         return swap32(v, lane);
}
__device__ __forceinline__ void fsincos(float rev, float* s, float* c){
#if __has_builtin(__builtin_amdgcn_sinf) && __has_builtin(__builtin_amdgcn_cosf)
    *s = __builtin_amdgcn_sinf(rev);   // HW: sin(rev * 2pi)
    *c = __builtin_amdgcn_cosf(rev);
#else
    __sincosf(rev * 6.2831853071795864f, s, c);
#endif
}

__global__ void precompute_kernel(const float* __restrict__ W_proj,
                                  const float* __restrict__ b_proj,
                                  const float* __restrict__ W_toq,
                                  const float* __restrict__ fP, const float* __restrict__ iP,
                                  const float* __restrict__ gP, const float* __restrict__ oP,
                                  float* __restrict__ ws)
{
    int tid = threadIdx.x;
    int blk = blockIdx.x;
    if (blk < 32) {
        int idx = blk * 256 + tid;
        int q = idx >> 10, dd = idx & 1023;
        float acc = 0.f;
        for (int p = 0; p < 64; ++p) acc += W_toq[q * 64 + p] * W_proj[p * 1024 + dd];
        if (dd < 512) ws[WS_WXQ + q * 512 + dd] = acc;
        else          ws[WS_WHQ + q * 512 + (dd - 512)] = acc;
        if (idx < 8) {
            float a2 = 0.f;
            for (int p = 0; p < 64; ++p) a2 += W_toq[idx * 64 + p] * b_proj[p];
            ws[WS_BQ + idx] = a2;
        }
    } else if (tid < 128) {
        int gt = tid >> 5, rest = tid & 31;
        const float* P = (gt == 0) ? fP : (gt == 1) ? iP : (gt == 2) ? gP : oP;
        int g = (rest >> 4) & 1, d = (rest >> 3) & 1, w = rest & 7;
        const float* p3 = P + (((g * 2 + d) * 8 + w) * 3);
        float a = 0.5f * p3[0], b = 0.5f * p3[1], c = 0.5f * p3[2];
        float ca = cosf(a), sa = sinf(a);
        float cb = cosf(b), sb = sinf(b);
        float cc = cosf(c), sc = sinf(c);
        c32 eb  = {cb, -sb};
        c32 ebc = {cb,  sb};
        c32 scx = {0.f, -sc};
        c32 m00 = { eb.x * ca,  eb.y * ca};
        c32 m01 = {-eb.x * sa, -eb.y * sa};
        c32 m10 = { ebc.x * sa, ebc.y * sa};
        c32 m11 = { ebc.x * ca, ebc.y * ca};
        c32 U00 = cadd(c32{cc * m00.x, cc * m00.y}, cmul(scx, m10));
        c32 U01 = cadd(c32{cc * m01.x, cc * m01.y}, cmul(scx, m11));
        c32 U10 = cadd(cmul(scx, m00), c32{cc * m10.x, cc * m10.y});
        c32 U11 = cadd(cmul(scx, m01), c32{cc * m11.x, cc * m11.y});
        float* dst = ws + WS_U + tid * 8;
        dst[0] = U00.x; dst[1] = U00.y; dst[2] = U01.x; dst[3] = U01.y;
        dst[4] = U10.x; dst[5] = U10.y; dst[6] = U11.x; dst[7] = U11.y;
    }
}

__global__ void xq_kernel(const float* __restrict__ inputs, float* __restrict__ ws)
{
    __shared__ float xs[512];
    int row = blockIdx.x;           // t*64 + b
    int tid = threadIdx.x;          // 256
    xs[tid]       = inputs[row * 512 + tid];
    xs[tid + 256] = inputs[row * 512 + 256 + tid];
    __syncthreads();
    int g = tid >> 5, j = tid & 31;
    const float* w = ws + WS_WXQ + g * 512;
    float acc = 0.f;
    #pragma unroll 4
    for (int i = 0; i < 16; ++i) acc += xs[j + 32 * i] * w[j + 32 * i];
    acc += __shfl_xor(acc, 1);  acc += __shfl_xor(acc, 2);
    acc += __shfl_xor(acc, 4);  acc += __shfl_xor(acc, 8);
    acc += __shfl_xor(acc, 16);
    if (j == 0) ws[WS_XQ + row * 8 + g] = acc + ws[WS_BQ + g];
}

// MPS-contraction recurrence: the 8-qubit circuit expectation values are computed
// via a bond-2 matrix-product contraction on 4 lanes per wave (lane c = m̃*2+m).
__global__ __launch_bounds__(256, 1)
void recurrence_kernel(const float* __restrict__ W_q2h,
                       const float* __restrict__ ws,
                       float* __restrict__ out)
{
    __shared__ __align__(16) float sU[1024];
    __shared__ __align__(16) float sXq[T_STEPS * 8];
    __shared__ __align__(16) float sexpW[4][8];   // [gate][q]
    __shared__ __align__(16) float qpartW[4][8];  // [gate][q]
    __shared__ __align__(16) float sH[T_STEPS * 512];  // h history (64 KB)

    int tid = threadIdx.x;   // 256
    int b   = blockIdx.x;    // 64
    int wv  = tid >> 6;
    int lane = tid & 63;

    for (int i = tid; i < 1024; i += 256) sU[i] = ws[WS_U + i];
    sXq[tid] = ws[WS_XQ + ((tid >> 3) * 64 + b) * 8 + (tid & 7)];
    if (tid < 32) ((float*)qpartW)[tid] = 0.f;

    // register-resident weights
    v2f wha2[4], whb2[4];
    #pragma unroll
    for (int j = 0; j < 4; ++j) {
        wha2[j] = mkv(ws[WS_WHQ + (2*j) * 512 + tid],       ws[WS_WHQ + (2*j+1) * 512 + tid]);
        whb2[j] = mkv(ws[WS_WHQ + (2*j) * 512 + tid + 256], ws[WS_WHQ + (2*j+1) * 512 + tid + 256]);
    }
    v2f w2hp[8];   // (W_q2h[tid][q], W_q2h[tid+256][q])
    {
        float4 a0 = *(const float4*)&W_q2h[tid * 8];
        float4 a1 = *(const float4*)&W_q2h[tid * 8 + 4];
        float4 b0 = *(const float4*)&W_q2h[(tid + 256) * 8];
        float4 b1 = *(const float4*)&W_q2h[(tid + 256) * 8 + 4];
        w2hp[0] = mkv(a0.x, b0.x); w2hp[1] = mkv(a0.y, b0.y);
        w2hp[2] = mkv(a0.z, b0.z); w2hp[3] = mkv(a0.w, b0.w);
        w2hp[4] = mkv(a1.x, b1.x); w2hp[5] = mkv(a1.y, b1.y);
        w2hp[6] = mkv(a1.z, b1.z); w2hp[7] = mkv(a1.w, b1.w);
    }

    __syncthreads();

    // ---- hoisted per-wave MPS constants ----
    // lane component: m = lane&1 (ket bond), mt = (lane>>1)&1 (bra bond); only lanes 0-3 carry state
    int m  = lane & 1;
    int mt = (lane >> 1) & 1;
    bool diag = (m == mt);

    // d0 column pairs: u_q[0] = ch*A0 + sh*B0 ; u_q[1] = ch*A1 + sh*B1  (B = -i*Ucol)
    v2f A0c[2][8], B0c[2][8], A1c[2][8], B1c[2][8];   // [gl][q]
    // per-site measurement matrices M_k = sum_j (-1)^j W[j,m] conj(W[j,m~]), per-lane component
    v2f Mc[2][8];                                      // [gl][site k]
    {
        #pragma unroll
        for (int gl = 0; gl < 2; ++gl) {
            #pragma unroll
            for (int q = 0; q < 8; ++q) {
                const float* d0m = sU + (wv * 32 + gl * 16 + q) * 8;
                A0c[gl][q] = mkv(d0m[0], d0m[1]);
                B0c[gl][q] = mkv(d0m[3], -d0m[2]);
                A1c[gl][q] = mkv(d0m[4], d0m[5]);
                B1c[gl][q] = mkv(d0m[7], -d0m[6]);
            }
            #pragma unroll
            for (int k = 0; k < 8; ++k) {
                const float* w1 = sU + (wv * 32 + gl * 16 + 8 + (7 - k)) * 8;  // wire 7-k acts on bit k
                // W00=(w1[0],w1[1]) W01=(w1[2],w1[3]) W10=(w1[4],w1[5]) W11=(w1[6],w1[7])
                float M00  = w1[0]*w1[0] + w1[1]*w1[1] - (w1[4]*w1[4] + w1[5]*w1[5]);
                float M11  = w1[2]*w1[2] + w1[3]*w1[3] - (w1[6]*w1[6] + w1[7]*w1[7]);
                float M01r = w1[0]*w1[2] + w1[1]*w1[3] - (w1[4]*w1[6] + w1[5]*w1[7]);
                float M01i = w1[1]*w1[2] - w1[0]*w1[3] - (w1[5]*w1[6] - w1[4]*w1[7]);
                float Mre = diag ? (m ? M11 : M00) : M01r;
                float Mim = diag ? 0.f : (mt ? M01i : -M01i);
                Mc[gl][k] = mkv(Mre, Mim);
            }
        }
    }

    const float REVC = 0.07957747154594767f;  // 0.5/(2*pi): hwsin(x*REVC) = sin(0.5*x)
    float c0 = 0.f, c1 = 0.f, h0 = 0.f, h1 = 0.f;

    // ================= recurrence =================
    for (int t = 0; t < T_STEPS; ++t) {
        // ---- angles (revolutions) ----
        float ang[8];
        {
            const v2f* qw = (const v2f*)qpartW;          // 16 v2f
            const v2f* xq2 = (const v2f*)&sXq[t * 8];    // 4 v2f
            #pragma unroll
            for (int j = 0; j < 4; ++j) {
                v2f s_ = ((qw[j] + qw[4 + j]) + (qw[8 + j] + qw[12 + j]) + xq2[j]) * REVC;
                ang[2 * j] = s_.x; ang[2 * j + 1] = s_.y;
            }
        }

        float e[8];
        #pragma unroll
        for (int gl = 0; gl < 2; ++gl) {
            float sh[8], ch[8];
            #pragma unroll
            for (int q = 0; q < 8; ++q) fsincos(ang[q], &sh[q], &ch[q]);

            // u-build (site-indexed: site k uses qubit 7-k)
            v2f U0[8], U1[8];
            #pragma unroll
            for (int q = 0; q < 8; ++q) {
                int k = 7 - q;
                U0[k] = ch[q] * A0c[gl][q] + sh[q] * B0c[gl][q];
                U1[k] = ch[q] * A1c[gl][q] + sh[q] * B1c[gl][q];
            }

            // bottom-up identity-channel closure Lb (diagonal recursion, scalar in all lanes)
            v2f Lb[8];
            Lb[0] = mkv(1.f, 0.f);
            float ld0 = 1.f, ld1 = 1.f;
            #pragma unroll
            for (int k = 0; k < 7; ++k) {
                v2f u0 = U0[k], u1 = U1[k];
                float n0 = u0.x*u0.x + u0.y*u0.y;
                float n1 = u1.x*u1.x + u1.y*u1.y;
                float wr = u0.x*u1.x + u0.y*u1.y;   // Re(u0*conj(u1))
                float wi = u0.y*u1.x - u0.x*u1.y;   // Im(u0*conj(u1))
                float offr = wr * (ld0 + ld1);
                float offi = wi * (ld0 - ld1);
                float t0 = n0*ld0 + n1*ld1;
                float t1 = n1*ld0 + n0*ld1;
                ld0 = t0; ld1 = t1;
                float Lre = diag ? (m ? ld1 : ld0) : offr;
                float Lim = diag ? 0.f : (mt ? offi : -offi);
                Lb[k + 1] = mkv(Lre, Lim);
            }

            // top-down Z-channel sweep + per-site dots
            v2f R = mkv(lane == 0 ? 1.f : 0.f, 0.f);
            float ep[8];
            #pragma unroll
            for (int kk = 0; kk < 8; ++kk) {
                const int k = 7 - kk;
                v2f u0 = U0[k], u1 = U1[k];
                v2f Rp = mkv(lanexor<1>(R.x, lane), lanexor<1>(R.y, lane));
                v2f A;
                A.x = u0.x*R.x - u0.y*R.y + u1.x*Rp.x - u1.y*Rp.y;
                A.y = u0.x*R.y + u0.y*R.x + u1.x*Rp.y + u1.y*Rp.x;
                v2f Ap = mkv(lanexor<2>(A.x, lane), lanexor<2>(A.y, lane));
                v2f B;
                B.x = u0.x*A.x + u0.y*A.y + u1.x*Ap.x + u1.y*Ap.y;   // conj(u0)*A + conj(u1)*Ap
                B.y = u0.x*A.y - u0.y*A.x + u1.x*Ap.y - u1.y*Ap.x;
                v2f Mv = Mc[gl][k];
                R.x = Mv.x*B.x - Mv.y*B.y;
                R.y = Mv.x*B.y + Mv.y*B.x;
                ep[kk] = R.x * Lb[k].x - R.y * Lb[k].y;   // Re(R . Lb) partial, e_{kk}
            }
            #pragma unroll
            for (int q = 0; q < 8; ++q) {
                ep[q] += lanexor<1>(ep[q], lane);
                ep[q] += lanexor<2>(ep[q], lane);
                e[q] = ep[q];
            }
            if (gl == 0) {
                #pragma unroll
                for (int q = 0; q < 8; ++q) ang[q] = e[q] * REVC;
            }
        }
        if (lane == 0) {
            float4 e0; e0.x = e[0]; e0.y = e[1]; e0.z = e[2]; e0.w = e[3];
            float4 e1; e1.x = e[4]; e1.y = e[5]; e1.z = e[6]; e1.w = e[7];
            *(float4*)&sexpW[wv][0] = e0;
            *(float4*)&sexpW[wv][4] = e1;
        }
        __syncthreads();

        // ---- LSTM cell: per-gate dots with packed (h0,h1) weights ----
        {
            v2f pre[4];
            #pragma unroll
            for (int g = 0; g < 4; ++g) {
                float4 ea = *(const float4*)&sexpW[g][0];
                float4 eb2 = *(const float4*)&sexpW[g][4];
                v2f acc = ea.x * w2hp[0] + ea.y * w2hp[1] + ea.z * w2hp[2] + ea.w * w2hp[3]
                        + eb2.x * w2hp[4] + eb2.y * w2hp[5] + eb2.z * w2hp[6] + eb2.w * w2hp[7];
                pre[g] = acc;
            }
            float f0 = fast_sigmoid(pre[0].x), i0 = fast_sigmoid(pre[1].x);
            float g0 = fast_tanh(pre[2].x),    o0 = fast_sigmoid(pre[3].x);
            c0 = f0 * c0 + i0 * g0;  h0 = o0 * fast_tanh(c0);
            float f1 = fast_sigmoid(pre[0].y), i1 = fast_sigmoid(pre[1].y);
            float g1 = fast_tanh(pre[2].y),    o1 = fast_sigmoid(pre[3].y);
            c1 = f1 * c1 + i1 * g1;  h1 = o1 * fast_tanh(c1);
            sH[t * 512 + tid]       = h0;
            sH[t * 512 + tid + 256] = h1;
        }

        // ---- qpart for next step ----
        {
            v2f pp[4];
            #pragma unroll
            for (int j = 0; j < 4; ++j) pp[j] = wha2[j] * h0 + whb2[j] * h1;
            #pragma unroll
            for (int j = 0; j < 4; ++j) {
                pp[j] += mkv(lanexor<1>(pp[j].x, lane), lanexor<1>(pp[j].y, lane));
                pp[j] += mkv(lanexor<2>(pp[j].x, lane), lanexor<2>(pp[j].y, lane));
                pp[j] += mkv(lanexor<4>(pp[j].x, lane), lanexor<4>(pp[j].y, lane));
            }
            int sel = lane & 7;
            float y = (sel == 0) ? pp[0].x : (sel == 1) ? pp[0].y
                    : (sel == 2) ? pp[1].x : (sel == 3) ? pp[1].y
                    : (sel == 4) ? pp[2].x : (sel == 5) ? pp[2].y
                    : (sel == 6) ? pp[3].x : pp[3].y;
            y += lanexor<8>(y, lane);
            y += swap16(y, lane);
            y += swap32(y, lane);
            if (lane < 8) qpartW[wv][lane] = y;
        }
        __syncthreads();
    }

    // bulk h-history copy + final hx, cx
    __syncthreads();
    {
        const float4* src = (const float4*)sH;
        float4* dst = (float4*)out;
        #pragma unroll
        for (int k = 0; k < 16; ++k) {
            int i = k * 256 + tid;          // float4 index, 4096 total
            int t = i >> 7, h4 = i & 127;
            dst[(t * 64 + b) * 128 + h4] = src[i];
        }
    }
    float* hx_out = out + (size_t)T_STEPS * 64 * 512;
    float* cx_out = hx_out + 64 * 512;
    hx_out[b * 512 + tid]       = h0;
    hx_out[b * 512 + tid + 256] = h1;
    cx_out[b * 512 + tid]       = c0;
    cx_out[b * 512 + tid + 256] = c1;
}

extern "C" void kernel_launch(void* const* d_in, const int* in_sizes, int n_in,
                              void* d_out, int out_size, void* d_ws, size_t ws_size,
                              hipStream_t stream)
{
    const float* inputs = (const float*)d_in[0];
    const float* W_proj = (const float*)d_in[1];
    const float* b_proj = (const float*)d_in[2];
    const float* W_toq  = (const float*)d_in[3];
    const float* W_q2h  = (const float*)d_in[4];
    const float* fP     = (const float*)d_in[5];
    const float* iP     = (const float*)d_in[6];
    const float* gP     = (const float*)d_in[7];
    const float* oP     = (const float*)d_in[8];
    float* ws  = (float*)d_ws;
    float* out = (float*)d_out;

    precompute_kernel<<<33, 256, 0, stream>>>(W_proj, b_proj, W_toq, fP, iP, gP, oP, ws);
    xq_kernel<<<T_STEPS * BATCH, 256, 0, stream>>>(inputs, ws);
    recurrence_kernel<<<BATCH, 256, 0, stream>>>(W_q2h, ws, out);
}